// Round 1
// baseline (340.476 us; speedup 1.0000x reference)
//
#include <hip/hip_runtime.h>

// ResGCN fused: out = (x @ ((C+I)W)^T + (C+I)b) / bl
// where C[o,s] = #edges with dst=o, src=s (edge indices live on the 256-channel axis).

constexpr int D = 256;      // D_IN == D_OUT
constexpr int TM = 128;     // m-tile
constexpr int TN = 128;     // o-tile
constexpr int BK = 16;      // k-chunk
constexpr int PITCH = 132;  // 128 + 4 pad -> staging writes are 2-way (free) not 4-way

// --- C = I ---------------------------------------------------------------
__global__ void init_c_kernel(float* __restrict__ C) {
    int i = blockIdx.x * 256 + threadIdx.x;
    int r = i >> 8, c = i & 255;
    C[i] = (r == c) ? 1.0f : 0.0f;
}

// --- C += edges (atomic; counts are small ints, exact in fp32) -----------
__global__ void scatter_edges_kernel(const int* __restrict__ em, int E,
                                     float* __restrict__ C) {
    int e = blockIdx.x * 256 + threadIdx.x;
    if (e < E) {
        int dst = em[e];
        int src = em[E + e];
        atomicAdd(&C[dst * D + src], 1.0f);
    }
}

// --- W2[o][i] = sum_s C[o][s] * W[s][i]  (256x256x256, noise) ------------
__global__ void fuse_w_kernel(const float* __restrict__ C, const float* __restrict__ W,
                              float* __restrict__ W2) {
    int o = blockIdx.x;
    int i = threadIdx.x;
    const float* Crow = C + o * D;   // uniform per block -> scalar loads
    float a0 = 0.f, a1 = 0.f, a2 = 0.f, a3 = 0.f;
    #pragma unroll 4
    for (int s = 0; s < D; s += 4) {
        a0 += Crow[s + 0] * W[(s + 0) * D + i];
        a1 += Crow[s + 1] * W[(s + 1) * D + i];
        a2 += Crow[s + 2] * W[(s + 2) * D + i];
        a3 += Crow[s + 3] * W[(s + 3) * D + i];
    }
    W2[o * D + i] = (a0 + a1) + (a2 + a3);
}

// --- b2[o] = sum_s C[o][s] * b[s] ----------------------------------------
__global__ void fuse_b_kernel(const float* __restrict__ C, const float* __restrict__ b,
                              float* __restrict__ b2) {
    int o = threadIdx.x;
    const float4* Crow = (const float4*)(C + o * D);
    const float4* b4 = (const float4*)b;
    float acc = 0.f;
    for (int s = 0; s < D / 4; ++s) {
        float4 c = Crow[s];
        float4 bb = b4[s];
        acc += c.x * bb.x + c.y * bb.y + c.z * bb.z + c.w * bb.w;
    }
    b2[o] = acc;
}

// --- main GEMM: out[m][o] = (x[m,:].W2[o,:] + b2[o]) / bl[m] -------------
// 256 threads, 128x128 tile, 8x8 micro-tile per thread with 4+4 split
// (o = tx*4..+3 and 64+tx*4..+3) so LDS read addresses alias <=2-way (free).
__global__ __launch_bounds__(256, 3) void resgcn_gemm_kernel(
    const float* __restrict__ X, const float* __restrict__ W2,
    const float* __restrict__ b2, const float* __restrict__ bl,
    float* __restrict__ out, int M)
{
    __shared__ float Xs[BK][PITCH];  // k-major (transposed) x tile
    __shared__ float Ws[BK][PITCH];  // k-major w tile

    const int tid = threadIdx.x;
    const int ty = tid >> 4;   // 0..15  -> m micro base ty*4 (+64)
    const int tx = tid & 15;   // 0..15  -> o micro base tx*4 (+64)
    const int m0 = blockIdx.y * TM;
    const int o0 = blockIdx.x * TN;

    const int lrow = tid >> 2;         // 0..63: which row of the 64-row half
    const int kseg = (tid & 3) * 4;    // which 4-float k segment

    float acc[8][8];
    #pragma unroll
    for (int i = 0; i < 8; ++i)
        #pragma unroll
        for (int j = 0; j < 8; ++j) acc[i][j] = 0.f;

    for (int k0 = 0; k0 < D; k0 += BK) {
        // global loads first (overlap with prior compute before the barrier)
        const int ma = m0 + lrow;
        const int mb = m0 + 64 + lrow;
        float4 xv0 = make_float4(0.f, 0.f, 0.f, 0.f);
        float4 xv1 = make_float4(0.f, 0.f, 0.f, 0.f);
        if (ma < M) xv0 = *(const float4*)&X[(size_t)ma * D + k0 + kseg];
        if (mb < M) xv1 = *(const float4*)&X[(size_t)mb * D + k0 + kseg];
        float4 wv0 = *(const float4*)&W2[(size_t)(o0 + lrow) * D + k0 + kseg];
        float4 wv1 = *(const float4*)&W2[(size_t)(o0 + 64 + lrow) * D + k0 + kseg];

        __syncthreads();  // previous iteration's LDS reads complete
        Xs[kseg + 0][lrow] = xv0.x;  Xs[kseg + 1][lrow] = xv0.y;
        Xs[kseg + 2][lrow] = xv0.z;  Xs[kseg + 3][lrow] = xv0.w;
        Xs[kseg + 0][64 + lrow] = xv1.x;  Xs[kseg + 1][64 + lrow] = xv1.y;
        Xs[kseg + 2][64 + lrow] = xv1.z;  Xs[kseg + 3][64 + lrow] = xv1.w;
        Ws[kseg + 0][lrow] = wv0.x;  Ws[kseg + 1][lrow] = wv0.y;
        Ws[kseg + 2][lrow] = wv0.z;  Ws[kseg + 3][lrow] = wv0.w;
        Ws[kseg + 0][64 + lrow] = wv1.x;  Ws[kseg + 1][64 + lrow] = wv1.y;
        Ws[kseg + 2][64 + lrow] = wv1.z;  Ws[kseg + 3][64 + lrow] = wv1.w;
        __syncthreads();

        #pragma unroll
        for (int kk = 0; kk < BK; ++kk) {
            float4 xa = *(const float4*)&Xs[kk][ty * 4];        // broadcast over tx
            float4 xb = *(const float4*)&Xs[kk][64 + ty * 4];
            float4 wa = *(const float4*)&Ws[kk][tx * 4];        // 2-way alias: free
            float4 wb = *(const float4*)&Ws[kk][64 + tx * 4];
            float xv[8] = {xa.x, xa.y, xa.z, xa.w, xb.x, xb.y, xb.z, xb.w};
            float wv[8] = {wa.x, wa.y, wa.z, wa.w, wb.x, wb.y, wb.z, wb.w};
            #pragma unroll
            for (int i = 0; i < 8; ++i)
                #pragma unroll
                for (int j = 0; j < 8; ++j)
                    acc[i][j] += xv[i] * wv[j];
        }
    }

    float4 ba  = *(const float4*)&b2[o0 + tx * 4];
    float4 bb4 = *(const float4*)&b2[o0 + 64 + tx * 4];
    float bo[8] = {ba.x, ba.y, ba.z, ba.w, bb4.x, bb4.y, bb4.z, bb4.w};

    #pragma unroll
    for (int i = 0; i < 8; ++i) {
        int m = m0 + ((i < 4) ? (ty * 4 + i) : (64 + ty * 4 + (i - 4)));
        if (m >= M) continue;
        float inv = 1.0f / bl[m];   // batch_lens division (ones in practice, but faithful)
        float4 r0, r1;
        r0.x = (acc[i][0] + bo[0]) * inv;
        r0.y = (acc[i][1] + bo[1]) * inv;
        r0.z = (acc[i][2] + bo[2]) * inv;
        r0.w = (acc[i][3] + bo[3]) * inv;
        r1.x = (acc[i][4] + bo[4]) * inv;
        r1.y = (acc[i][5] + bo[5]) * inv;
        r1.z = (acc[i][6] + bo[6]) * inv;
        r1.w = (acc[i][7] + bo[7]) * inv;
        *(float4*)&out[(size_t)m * D + o0 + tx * 4] = r0;
        *(float4*)&out[(size_t)m * D + o0 + 64 + tx * 4] = r1;
    }
}

extern "C" void kernel_launch(void* const* d_in, const int* in_sizes, int n_in,
                              void* d_out, int out_size, void* d_ws, size_t ws_size,
                              hipStream_t stream) {
    (void)n_in; (void)out_size; (void)ws_size;
    const float* X  = (const float*)d_in[0];   // [1, M, 256] fp32
    const float* W  = (const float*)d_in[1];   // [256, 256]  fp32
    const float* b  = (const float*)d_in[2];   // [256]       fp32
    const int*   em = (const int*)d_in[3];     // [2, E]      int
    const float* bl = (const float*)d_in[4];   // [M, 1]      fp32
    float* out = (float*)d_out;                // [1, M, 256] fp32

    const int M = in_sizes[0] / D;
    const int E = in_sizes[3] / 2;

    float* C  = (float*)d_ws;        // 256*256 fp32
    float* W2 = C + D * D;           // 256*256 fp32
    float* b2 = W2 + D * D;          // 256 fp32

    init_c_kernel<<<D * D / 256, 256, 0, stream>>>(C);
    scatter_edges_kernel<<<(E + 255) / 256, 256, 0, stream>>>(em, E, C);
    fuse_w_kernel<<<D, D, 0, stream>>>(C, W, W2);
    fuse_b_kernel<<<1, D, 0, stream>>>(C, b, b2);

    dim3 grid(D / TN, (M + TM - 1) / TM);
    resgcn_gemm_kernel<<<grid, 256, 0, stream>>>(X, W2, b2, bl, out, M);
}

// Round 2
// 217.740 us; speedup vs baseline: 1.5637x; 1.5637x over previous
//
#include <hip/hip_runtime.h>
#include <cstdint>

constexpr int D = 256;     // D_IN == D_OUT
constexpr int TM = 128;    // block m-tile; block o-tile = 256 (full) so X streams once

typedef __bf16 bf16x8 __attribute__((ext_vector_type(8)));
typedef float  f32x4  __attribute__((ext_vector_type(4)));

// ---- prep 1: W2 = W (fp32), b2 = b ------------------------------------
__global__ void prep_copy(const float* __restrict__ W, const float* __restrict__ b,
                          float* __restrict__ W2, float* __restrict__ b2) {
    int i = blockIdx.x * 256 + threadIdx.x;
    W2[i] = W[i];
    if (blockIdx.x == 0) b2[threadIdx.x] = b[threadIdx.x];
}

// ---- prep 2: per edge: W2[dst,:] += W[src,:]; b2[dst] += b[src] --------
// (C+I)W without ever forming C: only E=1024 edges.
__global__ void prep_edges(const int* __restrict__ em, int E,
                           const float* __restrict__ W, const float* __restrict__ b,
                           float* __restrict__ W2, float* __restrict__ b2) {
    int e = blockIdx.x;
    int k = threadIdx.x;
    int dst = em[e];
    int src = em[E + e];
    atomicAdd(&W2[dst * D + k], W[src * D + k]);
    if (k == 0) atomicAdd(&b2[dst], b[src]);
}

// ---- prep 3: W2 fp32 -> frag-order bf16 hi/lo -------------------------
// Layout per k-32 chunk kc: [o16b(16)][lane(64)][j(8)]  (8192 elems = 16 KB)
// B-frag (16x16x32): lane holds B[o = o16b*16 + (lane&15)][k = kc*32 + (lane>>4)*8 + j]
__global__ void prep_convert(const float* __restrict__ W2, ushort* __restrict__ Wh,
                             ushort* __restrict__ Wl) {
    int i = blockIdx.x * 256 + threadIdx.x;   // i = o*256 + k
    int o = i >> 8, k = i & 255;
    float x = W2[i];
    uint32_t u  = __float_as_uint(x);
    uint32_t hu = u & 0xFFFF0000u;            // hi = truncate to bf16
    float r = x - __uint_as_float(hu);        // exact residual
    uint32_t ru = __float_as_uint(r);
    uint32_t lu = ru + 0x7FFFu + ((ru >> 16) & 1u);   // RNE to bf16
    int kc = k >> 5, kk = k & 31, q = kk >> 3, j = kk & 7;
    int o16b = o >> 4;
    int lane = (o & 15) + 16 * q;
    int idx = kc * 8192 + (o16b * 64 + lane) * 8 + j;
    Wh[idx] = (ushort)(hu >> 16);
    Wl[idx] = (ushort)(lu >> 16);
}

// ---- helpers ----------------------------------------------------------
__device__ __forceinline__ void gl_lds16(const ushort* g, ushort* l) {
    __builtin_amdgcn_global_load_lds(
        (const __attribute__((address_space(1))) uint32_t*)g,
        (__attribute__((address_space(3))) uint32_t*)l, 16, 0, 0);
}

__device__ __forceinline__ void cvt8(const float4& f0, const float4& f1,
                                     uint4& hi, uint4& lo) {
    float xs[8] = {f0.x, f0.y, f0.z, f0.w, f1.x, f1.y, f1.z, f1.w};
    uint32_t h[8], l[8];
    #pragma unroll
    for (int j = 0; j < 8; ++j) {
        uint32_t u  = __float_as_uint(xs[j]);
        uint32_t hu = u & 0xFFFF0000u;
        h[j] = hu;
        float r = xs[j] - __uint_as_float(hu);
        uint32_t ru = __float_as_uint(r);
        l[j] = ru + 0x7FFFu + ((ru >> 16) & 1u);
    }
    hi = make_uint4((h[0] >> 16) | (h[1] & 0xFFFF0000u),
                    (h[2] >> 16) | (h[3] & 0xFFFF0000u),
                    (h[4] >> 16) | (h[5] & 0xFFFF0000u),
                    (h[6] >> 16) | (h[7] & 0xFFFF0000u));
    lo = make_uint4((l[0] >> 16) | (l[1] & 0xFFFF0000u),
                    (l[2] >> 16) | (l[3] & 0xFFFF0000u),
                    (l[4] >> 16) | (l[5] & 0xFFFF0000u),
                    (l[6] >> 16) | (l[7] & 0xFFFF0000u));
}

// ---- main: out[m,o] = (x[m,:].W2[o,:] + b2[o]) / bl[m] via split-bf16 MFMA
// block: 256 thr = 4 waves; tile m-128 x o-256; wave = m-128 x o-64 (mf=8, of=4)
__global__ __launch_bounds__(256, 2) void resgcn_mfma(
    const float* __restrict__ X, const ushort* __restrict__ Whg,
    const ushort* __restrict__ Wlg, const float* __restrict__ b2,
    const float* __restrict__ blen, float* __restrict__ out, int M)
{
    __shared__ ushort Xh[8][64][8];    // [m16b][lane][j]  8 KB
    __shared__ ushort Xl[8][64][8];
    __shared__ ushort Wh[16][64][8];   // [o16b][lane][j] 16 KB
    __shared__ ushort Wl[16][64][8];

    const int tid  = threadIdx.x;
    const int lane = tid & 63;
    const int wv   = tid >> 6;                 // wave's o-quadrant (o16b = wv*4+b)
    const int m0   = blockIdx.x * TM;

    // X staging coords: thread covers row sm, 16-k half sh of each 32-k chunk
    const int sm = tid >> 1;
    const int sh = tid & 1;
    int srow = m0 + sm; if (srow >= M) srow = M - 1;   // clamp: real data, no NaN
    const float* xrow = X + (size_t)srow * D + sh * 16;
    const int m16b = sm >> 4;
    const int mlow = sm & 15;

    f32x4 acc[8][4];
    #pragma unroll
    for (int a = 0; a < 8; ++a)
        #pragma unroll
        for (int b = 0; b < 4; ++b) acc[a][b] = (f32x4){0.f, 0.f, 0.f, 0.f};

    for (int kc = 0; kc < 8; ++kc) {
        __syncthreads();   // previous chunk's LDS reads complete

        // async stage W hi/lo (16 KB each), already frag-ordered in global
        {
            const ushort* gh = Whg + kc * 8192;
            const ushort* gl = Wlg + kc * 8192;
            ushort* lh = &Wh[0][0][0];
            ushort* ll = &Wl[0][0][0];
            #pragma unroll
            for (int i = 0; i < 4; ++i) {
                int off = (i * 256 + tid) * 8;
                gl_lds16(gh + off, lh + off);
                gl_lds16(gl + off, ll + off);
            }
        }

        // stage X: 16 fp32 contiguous -> hi/lo bf16 frag-order, 4 ds_write_b128
        {
            const float* p = xrow + kc * 32;
            float4 f0 = *(const float4*)(p + 0);
            float4 f1 = *(const float4*)(p + 4);
            float4 f2 = *(const float4*)(p + 8);
            float4 f3 = *(const float4*)(p + 12);
            uint4 h0, l0, h1, l1;
            cvt8(f0, f1, h0, l0);
            cvt8(f2, f3, h1, l1);
            const int q0 = sh * 2, q1 = sh * 2 + 1;
            *(uint4*)&Xh[m16b][mlow + 16 * q0][0] = h0;
            *(uint4*)&Xl[m16b][mlow + 16 * q0][0] = l0;
            *(uint4*)&Xh[m16b][mlow + 16 * q1][0] = h1;
            *(uint4*)&Xl[m16b][mlow + 16 * q1][0] = l1;
        }

        __syncthreads();   // drains global_load_lds (vmcnt) + ds_writes

        bf16x8 bh[4], blo[4];
        #pragma unroll
        for (int b = 0; b < 4; ++b) {
            bh[b]  = *(const bf16x8*)&Wh[wv * 4 + b][lane][0];
            blo[b] = *(const bf16x8*)&Wl[wv * 4 + b][lane][0];
        }
        #pragma unroll
        for (int a = 0; a < 8; ++a) {
            bf16x8 ah = *(const bf16x8*)&Xh[a][lane][0];
            bf16x8 al = *(const bf16x8*)&Xl[a][lane][0];
            #pragma unroll
            for (int b = 0; b < 4; ++b) {
                acc[a][b] = __builtin_amdgcn_mfma_f32_16x16x32_bf16(ah, bh[b],  acc[a][b], 0, 0, 0);
                acc[a][b] = __builtin_amdgcn_mfma_f32_16x16x32_bf16(al, bh[b],  acc[a][b], 0, 0, 0);
                acc[a][b] = __builtin_amdgcn_mfma_f32_16x16x32_bf16(ah, blo[b], acc[a][b], 0, 0, 0);
            }
        }
    }

    // epilogue: C/D layout col=lane&15, row=(lane>>4)*4+reg  (m89-verified)
    const int col = lane & 15;
    const int rq  = lane >> 4;
    float bias[4];
    #pragma unroll
    for (int b = 0; b < 4; ++b) bias[b] = b2[(wv * 4 + b) * 16 + col];

    #pragma unroll
    for (int a = 0; a < 8; ++a) {
        #pragma unroll
        for (int r = 0; r < 4; ++r) {
            int m = m0 + a * 16 + rq * 4 + r;
            if (m < M) {
                float inv = 1.0f / blen[m];
                #pragma unroll
                for (int b = 0; b < 4; ++b) {
                    int o = (wv * 4 + b) * 16 + col;
                    out[(size_t)m * D + o] = (acc[a][b][r] + bias[b]) * inv;
                }
            }
        }
    }
}

extern "C" void kernel_launch(void* const* d_in, const int* in_sizes, int n_in,
                              void* d_out, int out_size, void* d_ws, size_t ws_size,
                              hipStream_t stream) {
    (void)n_in; (void)out_size; (void)ws_size;
    const float* X  = (const float*)d_in[0];
    const float* W  = (const float*)d_in[1];
    const float* b  = (const float*)d_in[2];
    const int*   em = (const int*)d_in[3];
    const float* bl = (const float*)d_in[4];
    float* out = (float*)d_out;

    const int M = in_sizes[0] / D;
    const int E = in_sizes[3] / 2;

    float*  W2 = (float*)d_ws;            // 65536 fp32
    float*  b2 = W2 + D * D;              // 256 fp32
    ushort* Wh = (ushort*)(b2 + D);       // 65536 bf16 (16B-aligned offset)
    ushort* Wl = Wh + D * D;              // 65536 bf16

    prep_copy<<<D * D / 256, 256, 0, stream>>>(W, b, W2, b2);
    prep_edges<<<E, D, 0, stream>>>(em, E, W, b, W2, b2);
    prep_convert<<<D * D / 256, 256, 0, stream>>>(W2, Wh, Wl);

    int mblocks = (M + TM - 1) / TM;
    resgcn_mfma<<<mblocks, 256, 0, stream>>>(X, Wh, Wl, b2, bl, out, M);
}